// Round 1
// baseline (832.985 us; speedup 1.0000x reference)
//
#include <hip/hip_runtime.h>

#define N_NODES 50000
#define N_EDGES 800000

// ---------------- CSR build ----------------

__global__ void hist_kernel(const int* __restrict__ dst, int* __restrict__ deg) {
    int i = blockIdx.x * 256 + threadIdx.x;
    if (i < N_EDGES) atomicAdd(&deg[dst[i]], 1);
}

__global__ void scan_kernel(const int* __restrict__ deg, int* __restrict__ row_ptr,
                            int* __restrict__ fill_pos) {
    __shared__ int part[1024];
    int t = threadIdx.x;
    const int CH = (N_NODES + 1023) / 1024;  // 49
    int base = t * CH;
    int s = 0;
    for (int i = 0; i < CH; i++) {
        int idx = base + i;
        if (idx < N_NODES) s += deg[idx];
    }
    part[t] = s;
    __syncthreads();
    for (int off = 1; off < 1024; off <<= 1) {
        int v = part[t];
        int add = (t >= off) ? part[t - off] : 0;
        __syncthreads();
        part[t] = v + add;
        __syncthreads();
    }
    int run = (t > 0) ? part[t - 1] : 0;
    for (int i = 0; i < CH; i++) {
        int idx = base + i;
        if (idx < N_NODES) {
            row_ptr[idx] = run;
            fill_pos[idx] = run;
            run += deg[idx];
        }
    }
    if (t == 0) row_ptr[N_NODES] = part[1023];
}

__global__ void fill_kernel(const int* __restrict__ src, const int* __restrict__ dst,
                            int* __restrict__ fill_pos, int* __restrict__ esrc) {
    int i = blockIdx.x * 256 + threadIdx.x;
    if (i < N_EDGES) {
        int p = atomicAdd(&fill_pos[dst[i]], 1);
        esrc[p] = src[i];
    }
}

// ---------------- Aggregation: u = (1+eps)*h + mean_{in}(h) ----------------
// One wave (64 lanes) per node; lane holds feature pair [2*lane, 2*lane+1].

__global__ void agg_kernel(const float* __restrict__ h, const int* __restrict__ row_ptr,
                           const int* __restrict__ esrc, const float* __restrict__ eps,
                           int layer, float* __restrict__ u) {
    int gtid = blockIdx.x * 256 + threadIdx.x;
    int node = gtid >> 6;
    int lane = threadIdx.x & 63;
    if (node >= N_NODES) return;
    node = __builtin_amdgcn_readfirstlane(node);  // wave-uniform: scalarize CSR walk
    int beg = row_ptr[node];
    int end = row_ptr[node + 1];
    beg = __builtin_amdgcn_readfirstlane(beg);
    end = __builtin_amdgcn_readfirstlane(end);

    const float* hl = h + lane * 2;
    float a0x = 0.f, a0y = 0.f, a1x = 0.f, a1y = 0.f;
    float a2x = 0.f, a2y = 0.f, a3x = 0.f, a3y = 0.f;
    int e = beg;
    for (; e + 3 < end; e += 4) {
        int s0 = esrc[e], s1 = esrc[e + 1], s2 = esrc[e + 2], s3 = esrc[e + 3];
        float2 v0 = *(const float2*)(hl + (size_t)s0 * 128);
        float2 v1 = *(const float2*)(hl + (size_t)s1 * 128);
        float2 v2 = *(const float2*)(hl + (size_t)s2 * 128);
        float2 v3 = *(const float2*)(hl + (size_t)s3 * 128);
        a0x += v0.x; a0y += v0.y;
        a1x += v1.x; a1y += v1.y;
        a2x += v2.x; a2y += v2.y;
        a3x += v3.x; a3y += v3.y;
    }
    for (; e < end; e++) {
        int s = esrc[e];
        float2 v = *(const float2*)(hl + (size_t)s * 128);
        a0x += v.x; a0y += v.y;
    }
    float sx = (a0x + a1x) + (a2x + a3x);
    float sy = (a0y + a1y) + (a2y + a3y);
    int d = end - beg;
    float inv = (d > 0) ? 1.0f / (float)d : 0.0f;
    float ep = 1.0f + eps[layer];
    float2 hv = *(const float2*)(hl + (size_t)node * 128);
    float2 r;
    r.x = ep * hv.x + sx * inv;
    r.y = ep * hv.y + sy * inv;
    *(float2*)(u + (size_t)node * 128 + lane * 2) = r;
}

// ---------------- Row-per-thread GEMM: out[r][c] = relu?(dot(U[r], W[c]) + bias[c]) ----
// U row (128 fp32) held in VGPRs; W/bias accesses are wave-uniform -> s_load;
// inner loop is pure v_fma_f32 with SGPR weight operands (no LDS).
// gridDim.y splits columns (CPB per block) for occupancy.

template <int COLS, int CPB, bool RELU>
__global__ void __launch_bounds__(256) gemm_kernel(const float* __restrict__ U,
                                                   const float* __restrict__ W,
                                                   const float* __restrict__ bias,
                                                   float* __restrict__ out, int nrows) {
    int row = blockIdx.x * 256 + threadIdx.x;
    if (row >= nrows) return;
    int c0 = blockIdx.y * CPB;

    float ur[128];
    const float4* up = (const float4*)(U + (size_t)row * 128);
#pragma unroll
    for (int q = 0; q < 32; q++) ((float4*)ur)[q] = up[q];

    float* orow = out + (size_t)row * COLS;
    for (int cb = c0; cb < c0 + CPB; cb += 4) {
        float a0 = bias[cb + 0];
        float a1 = bias[cb + 1];
        float a2 = bias[cb + 2];
        float a3 = bias[cb + 3];
        const float* w0 = W + (size_t)(cb + 0) * 128;
        const float* w1 = W + (size_t)(cb + 1) * 128;
        const float* w2 = W + (size_t)(cb + 2) * 128;
        const float* w3 = W + (size_t)(cb + 3) * 128;
#pragma unroll
        for (int k = 0; k < 128; k++) {
            float uk = ur[k];
            a0 = fmaf(uk, w0[k], a0);
            a1 = fmaf(uk, w1[k], a1);
            a2 = fmaf(uk, w2[k], a2);
            a3 = fmaf(uk, w3[k], a3);
        }
        if (RELU) {
            a0 = fmaxf(a0, 0.f);
            a1 = fmaxf(a1, 0.f);
            a2 = fmaxf(a2, 0.f);
            a3 = fmaxf(a3, 0.f);
        }
        float4 res = {a0, a1, a2, a3};
        *(float4*)(orow + cb) = res;
    }
}

// ---------------- launch ----------------

extern "C" void kernel_launch(void* const* d_in, const int* in_sizes, int n_in,
                              void* d_out, int out_size, void* d_ws, size_t ws_size,
                              hipStream_t stream) {
    const float* X   = (const float*)d_in[0];  // [50000,128]
    const float* fcW = (const float*)d_in[1];  // [128,128]
    const float* fcb = (const float*)d_in[2];  // [128]
    const float* W   = (const float*)d_in[3];  // [3,128,128]
    const float* b   = (const float*)d_in[4];  // [3,128]
    const float* Wl  = (const float*)d_in[5];  // [64,128]
    const float* bl  = (const float*)d_in[6];  // [64]
    const float* eps = (const float*)d_in[7];  // [4]
    const int* src   = (const int*)d_in[8];    // [800000]
    const int* dst   = (const int*)d_in[9];    // [800000]
    float* out = (float*)d_out;                // [50000,64]

    // workspace carve (~55 MB)
    float* h = (float*)d_ws;                          // 50000*128 f32
    float* u = h + (size_t)N_NODES * 128;             // 50000*128 f32
    int* deg      = (int*)(u + (size_t)N_NODES * 128);
    int* row_ptr  = deg + N_NODES;                    // N_NODES+1
    int* fill_pos = row_ptr + (N_NODES + 1);
    int* esrc     = fill_pos + N_NODES;               // N_EDGES

    // CSR build (deg -> row_ptr -> slot scatter); same for all 4 layers
    hipMemsetAsync(deg, 0, N_NODES * sizeof(int), stream);
    hist_kernel<<<N_EDGES / 256, 256, 0, stream>>>(dst, deg);
    scan_kernel<<<1, 1024, 0, stream>>>(deg, row_ptr, fill_pos);
    fill_kernel<<<N_EDGES / 256, 256, 0, stream>>>(src, dst, fill_pos, esrc);

    const int gx = (N_NODES + 255) / 256;        // 196 row-blocks
    const int agg_blocks = (N_NODES * 64 + 255) / 256;  // 12500

    // input SLP: h = relu(X @ fcW^T + fcb)
    gemm_kernel<128, 32, true><<<dim3(gx, 4), 256, 0, stream>>>(X, fcW, fcb, h, N_NODES);

    // 3 hidden GIN layers
    for (int i = 0; i < 3; i++) {
        agg_kernel<<<agg_blocks, 256, 0, stream>>>(h, row_ptr, esrc, eps, i, u);
        gemm_kernel<128, 32, true><<<dim3(gx, 4), 256, 0, stream>>>(
            u, W + (size_t)i * 128 * 128, b + (size_t)i * 128, h, N_NODES);
    }

    // last layer (no relu), writes d_out
    agg_kernel<<<agg_blocks, 256, 0, stream>>>(h, row_ptr, esrc, eps, 3, u);
    gemm_kernel<64, 32, false><<<dim3(gx, 2), 256, 0, stream>>>(u, Wl, bl, out, N_NODES);
}

// Round 2
// 576.315 us; speedup vs baseline: 1.4454x; 1.4454x over previous
//
#include <hip/hip_runtime.h>

#define N_NODES 50000
#define N_EDGES 800000

typedef __attribute__((ext_vector_type(8))) short short8;
typedef __attribute__((ext_vector_type(4))) float float4v;

__device__ inline unsigned short f2bf(float f) {
    unsigned u = __float_as_uint(f);
    unsigned r = u + 0x7fff + ((u >> 16) & 1);
    return (unsigned short)(r >> 16);
}
__device__ inline float bf2f(unsigned short h) {
    return __uint_as_float(((unsigned)h) << 16);
}

// ---------------- CSR build ----------------

__global__ void hist_kernel(const int* __restrict__ dst, int* __restrict__ deg) {
    int i = blockIdx.x * 256 + threadIdx.x;
    if (i < N_EDGES) atomicAdd(&deg[dst[i]], 1);
}

// phase 1: per-256-block sums
__global__ void scan_partial(const int* __restrict__ deg, int* __restrict__ partial) {
    __shared__ int sm[256];
    int t = threadIdx.x;
    int i = blockIdx.x * 256 + t;
    sm[t] = (i < N_NODES) ? deg[i] : 0;
    __syncthreads();
    for (int o = 128; o > 0; o >>= 1) {
        if (t < o) sm[t] += sm[t + o];
        __syncthreads();
    }
    if (t == 0) partial[blockIdx.x] = sm[0];
}

// phase 2: exclusive-scan the 196 partials (single small block); also total -> row_ptr[N]
__global__ void scan_offsets(int* __restrict__ partial, int* __restrict__ row_ptr, int nparts) {
    __shared__ int sm[256];
    int t = threadIdx.x;
    int v = (t < nparts) ? partial[t] : 0;
    sm[t] = v;
    __syncthreads();
    for (int o = 1; o < 256; o <<= 1) {
        int x = sm[t];
        int a = (t >= o) ? sm[t - o] : 0;
        __syncthreads();
        sm[t] = x + a;
        __syncthreads();
    }
    if (t < nparts) partial[t] = sm[t] - v;  // exclusive
    if (t == nparts - 1) row_ptr[N_NODES] = sm[t];
}

// phase 3: per-block exclusive scan + block offset
__global__ void scan_final(const int* __restrict__ deg, const int* __restrict__ partial,
                           int* __restrict__ row_ptr, int* __restrict__ fill_pos) {
    __shared__ int sm[256];
    int t = threadIdx.x;
    int i = blockIdx.x * 256 + t;
    int v = (i < N_NODES) ? deg[i] : 0;
    sm[t] = v;
    __syncthreads();
    for (int o = 1; o < 256; o <<= 1) {
        int x = sm[t];
        int a = (t >= o) ? sm[t - o] : 0;
        __syncthreads();
        sm[t] = x + a;
        __syncthreads();
    }
    if (i < N_NODES) {
        int ex = sm[t] - v + partial[blockIdx.x];
        row_ptr[i] = ex;
        fill_pos[i] = ex;
    }
}

__global__ void fill_kernel(const int* __restrict__ src, const int* __restrict__ dst,
                            int* __restrict__ fill_pos, int* __restrict__ esrc) {
    int i = blockIdx.x * 256 + threadIdx.x;
    if (i < N_EDGES) {
        int p = atomicAdd(&fill_pos[dst[i]], 1);
        esrc[p] = src[i];
    }
}

// ---------------- weight split: W -> W_hi + W_lo (bf16 pair, ~16-bit mantissa) ------
// layout: [0,16384) fcW | [16384,65536) W(3 layers) | [65536,73728) W_last
__global__ void prep_weights(const float* __restrict__ fcW, const float* __restrict__ W,
                             const float* __restrict__ Wl, unsigned short* __restrict__ hi,
                             unsigned short* __restrict__ lo) {
    int i = blockIdx.x * 256 + threadIdx.x;
    float v;
    if (i < 16384) v = fcW[i];
    else if (i < 65536) v = W[i - 16384];
    else if (i < 73728) v = Wl[i - 65536];
    else return;
    unsigned short h = f2bf(v);
    hi[i] = h;
    lo[i] = f2bf(v - bf2f(h));
}

// ---------------- Aggregation: u = (1+eps)*h + mean_{in}(h) ----------------
// One wave per node; lane holds feature pair [2*lane, 2*lane+1]. fp32 throughout.

__global__ void agg_kernel(const float* __restrict__ h, const int* __restrict__ row_ptr,
                           const int* __restrict__ esrc, const float* __restrict__ eps,
                           int layer, float* __restrict__ u) {
    int gtid = blockIdx.x * 256 + threadIdx.x;
    int node = gtid >> 6;
    int lane = threadIdx.x & 63;
    if (node >= N_NODES) return;
    node = __builtin_amdgcn_readfirstlane(node);
    int beg = __builtin_amdgcn_readfirstlane(row_ptr[node]);
    int end = __builtin_amdgcn_readfirstlane(row_ptr[node + 1]);

    const float* hl = h + lane * 2;
    float a0x = 0.f, a0y = 0.f, a1x = 0.f, a1y = 0.f;
    float a2x = 0.f, a2y = 0.f, a3x = 0.f, a3y = 0.f;
    int e = beg;
    for (; e + 3 < end; e += 4) {
        int s0 = esrc[e], s1 = esrc[e + 1], s2 = esrc[e + 2], s3 = esrc[e + 3];
        float2 v0 = *(const float2*)(hl + (size_t)s0 * 128);
        float2 v1 = *(const float2*)(hl + (size_t)s1 * 128);
        float2 v2 = *(const float2*)(hl + (size_t)s2 * 128);
        float2 v3 = *(const float2*)(hl + (size_t)s3 * 128);
        a0x += v0.x; a0y += v0.y;
        a1x += v1.x; a1y += v1.y;
        a2x += v2.x; a2y += v2.y;
        a3x += v3.x; a3y += v3.y;
    }
    for (; e < end; e++) {
        int s = esrc[e];
        float2 v = *(const float2*)(hl + (size_t)s * 128);
        a0x += v.x; a0y += v.y;
    }
    float sx = (a0x + a1x) + (a2x + a3x);
    float sy = (a0y + a1y) + (a2y + a3y);
    int d = end - beg;
    float inv = (d > 0) ? 1.0f / (float)d : 0.0f;
    float ep = 1.0f + eps[layer];
    float2 hv = *(const float2*)(hl + (size_t)node * 128);
    float2 r;
    r.x = ep * hv.x + sx * inv;
    r.y = ep * hv.y + sy * inv;
    *(float2*)(u + (size_t)node * 128 + lane * 2) = r;
}

// ---------------- split-bf16 MFMA GEMM ----------------
// C[r][n] = relu?(sum_k U[r][k]*W[n][k] + bias[n]);  U fp32 split on the fly,
// W pre-split hi/lo.  D = Ahi*Whi + Alo*Whi + Ahi*Wlo  (missing Alo*Wlo ~ 2^-18).
// Block = 4 waves = 64 rows; wave w -> rows [bx*64+w*16, +16).  No LDS.
// A frag (16x16x32): lane holds A[m=lane&15][k=quad*8+j]; B frag same with n=lane&15.
// C/D frag: col=lane&15, row=quad*4+reg  [verified m89/m91].

template <int COLS, bool RELU>
__global__ void __launch_bounds__(256) gemm_mfma(const float* __restrict__ U,
                                                 const unsigned short* __restrict__ Whi,
                                                 const unsigned short* __restrict__ Wlo,
                                                 const float* __restrict__ bias,
                                                 float* __restrict__ out, int nrows) {
    int wave = threadIdx.x >> 6;
    int lane = threadIdx.x & 63;
    int m = lane & 15;
    int quad = lane >> 4;
    int r0 = blockIdx.x * 64 + wave * 16;
    int rowA = r0 + m;
    if (rowA >= nrows) rowA = nrows - 1;  // clamp OOB loads (stores guarded)

    // load U row fragment, split into hi/lo bf16
    short8 ahi[4], alo[4];
    const float* arow = U + (size_t)rowA * 128 + quad * 8;
#pragma unroll
    for (int kc = 0; kc < 4; kc++) {
        float4 f0 = *(const float4*)(arow + kc * 32);
        float4 f1 = *(const float4*)(arow + kc * 32 + 4);
        float fv[8] = {f0.x, f0.y, f0.z, f0.w, f1.x, f1.y, f1.z, f1.w};
#pragma unroll
        for (int j = 0; j < 8; j++) {
            unsigned short h = f2bf(fv[j]);
            ahi[kc][j] = (short)h;
            alo[kc][j] = (short)f2bf(fv[j] - bf2f(h));
        }
    }

#pragma unroll
    for (int nt = 0; nt < COLS / 16; nt++) {
        int n = nt * 16 + m;
        const unsigned short* bhp = Whi + (size_t)n * 128 + quad * 8;
        const unsigned short* blp = Wlo + (size_t)n * 128 + quad * 8;
        float4v acc = {0.f, 0.f, 0.f, 0.f};
#pragma unroll
        for (int kc = 0; kc < 4; kc++) {
            short8 bh = *(const short8*)(bhp + kc * 32);
            short8 bl = *(const short8*)(blp + kc * 32);
            acc = __builtin_amdgcn_mfma_f32_16x16x32_bf16(ahi[kc], bh, acc, 0, 0, 0);
            acc = __builtin_amdgcn_mfma_f32_16x16x32_bf16(alo[kc], bh, acc, 0, 0, 0);
            acc = __builtin_amdgcn_mfma_f32_16x16x32_bf16(ahi[kc], bl, acc, 0, 0, 0);
        }
        float bv = bias[n];
#pragma unroll
        for (int i = 0; i < 4; i++) {
            int r = r0 + quad * 4 + i;
            if (r < nrows) {
                float v = acc[i] + bv;
                if (RELU) v = fmaxf(v, 0.f);
                out[(size_t)r * COLS + n] = v;
            }
        }
    }
}

// ---------------- launch ----------------

extern "C" void kernel_launch(void* const* d_in, const int* in_sizes, int n_in,
                              void* d_out, int out_size, void* d_ws, size_t ws_size,
                              hipStream_t stream) {
    const float* X   = (const float*)d_in[0];
    const float* fcW = (const float*)d_in[1];
    const float* fcb = (const float*)d_in[2];
    const float* W   = (const float*)d_in[3];
    const float* b   = (const float*)d_in[4];
    const float* Wl  = (const float*)d_in[5];
    const float* bl  = (const float*)d_in[6];
    const float* eps = (const float*)d_in[7];
    const int* src   = (const int*)d_in[8];
    const int* dst   = (const int*)d_in[9];
    float* out = (float*)d_out;

    // workspace carve
    float* h = (float*)d_ws;                              // 50000*128 f32
    float* u = h + (size_t)N_NODES * 128;                 // 50000*128 f32
    unsigned short* whi = (unsigned short*)(u + (size_t)N_NODES * 128);  // 73728 bf16
    unsigned short* wlo = whi + 73728;                    // 73728 bf16
    int* deg      = (int*)(wlo + 73728);
    int* row_ptr  = deg + N_NODES;                        // N_NODES+1
    int* fill_pos = row_ptr + (N_NODES + 1);
    int* partial  = fill_pos + N_NODES;                   // 256
    int* esrc     = partial + 256;                        // N_EDGES

    const int NB = (N_NODES + 255) / 256;  // 196

    // weight split (independent)
    prep_weights<<<(73728 + 255) / 256, 256, 0, stream>>>(fcW, W, Wl, whi, wlo);

    // CSR build
    hipMemsetAsync(deg, 0, N_NODES * sizeof(int), stream);
    hist_kernel<<<N_EDGES / 256, 256, 0, stream>>>(dst, deg);
    scan_partial<<<NB, 256, 0, stream>>>(deg, partial);
    scan_offsets<<<1, 256, 0, stream>>>(partial, row_ptr, NB);
    scan_final<<<NB, 256, 0, stream>>>(deg, partial, row_ptr, fill_pos);
    fill_kernel<<<N_EDGES / 256, 256, 0, stream>>>(src, dst, fill_pos, esrc);

    const int gemm_blocks = (N_NODES + 63) / 64;            // 782
    const int agg_blocks = (N_NODES * 64 + 255) / 256;      // 12500

    // input SLP: h = relu(X @ fcW^T + fcb)
    gemm_mfma<128, true><<<gemm_blocks, 256, 0, stream>>>(X, whi, wlo, fcb, h, N_NODES);

    // 3 hidden GIN layers
    for (int i = 0; i < 3; i++) {
        agg_kernel<<<agg_blocks, 256, 0, stream>>>(h, row_ptr, esrc, eps, i, u);
        gemm_mfma<128, true><<<gemm_blocks, 256, 0, stream>>>(
            u, whi + 16384 + (size_t)i * 16384, wlo + 16384 + (size_t)i * 16384,
            b + (size_t)i * 128, h, N_NODES);
    }

    // last layer (no relu) -> d_out
    agg_kernel<<<agg_blocks, 256, 0, stream>>>(h, row_ptr, esrc, eps, 3, u);
    gemm_mfma<64, false><<<gemm_blocks, 256, 0, stream>>>(u, whi + 65536, wlo + 65536, bl, out,
                                                          N_NODES);
}

// Round 3
// 488.171 us; speedup vs baseline: 1.7063x; 1.1806x over previous
//
#include <hip/hip_runtime.h>

#define N_NODES 50000
#define N_EDGES 800000

typedef __attribute__((ext_vector_type(8))) short short8;
typedef __attribute__((ext_vector_type(4))) float float4v;

__device__ inline unsigned short f2bf(float f) {
    unsigned u = __float_as_uint(f);
    unsigned r = u + 0x7fff + ((u >> 16) & 1);
    return (unsigned short)(r >> 16);
}
__device__ inline float bf2f(unsigned short h) {
    return __uint_as_float(((unsigned)h) << 16);
}

// ---------------- CSR build ----------------

__global__ void hist_kernel(const int* __restrict__ dst, int* __restrict__ deg) {
    int i = blockIdx.x * 256 + threadIdx.x;
    if (i < N_EDGES) atomicAdd(&deg[dst[i]], 1);
}

__global__ void scan_partial(const int* __restrict__ deg, int* __restrict__ partial) {
    __shared__ int sm[256];
    int t = threadIdx.x;
    int i = blockIdx.x * 256 + t;
    sm[t] = (i < N_NODES) ? deg[i] : 0;
    __syncthreads();
    for (int o = 128; o > 0; o >>= 1) {
        if (t < o) sm[t] += sm[t + o];
        __syncthreads();
    }
    if (t == 0) partial[blockIdx.x] = sm[0];
}

__global__ void scan_offsets(int* __restrict__ partial, int* __restrict__ row_ptr, int nparts) {
    __shared__ int sm[256];
    int t = threadIdx.x;
    int v = (t < nparts) ? partial[t] : 0;
    sm[t] = v;
    __syncthreads();
    for (int o = 1; o < 256; o <<= 1) {
        int x = sm[t];
        int a = (t >= o) ? sm[t - o] : 0;
        __syncthreads();
        sm[t] = x + a;
        __syncthreads();
    }
    if (t < nparts) partial[t] = sm[t] - v;  // exclusive
    if (t == nparts - 1) row_ptr[N_NODES] = sm[t];
}

__global__ void scan_final(const int* __restrict__ deg, const int* __restrict__ partial,
                           int* __restrict__ row_ptr, int* __restrict__ fill_pos) {
    __shared__ int sm[256];
    int t = threadIdx.x;
    int i = blockIdx.x * 256 + t;
    int v = (i < N_NODES) ? deg[i] : 0;
    sm[t] = v;
    __syncthreads();
    for (int o = 1; o < 256; o <<= 1) {
        int x = sm[t];
        int a = (t >= o) ? sm[t - o] : 0;
        __syncthreads();
        sm[t] = x + a;
        __syncthreads();
    }
    if (i < N_NODES) {
        int ex = sm[t] - v + partial[blockIdx.x];
        row_ptr[i] = ex;
        fill_pos[i] = ex;
    }
}

__global__ void fill_kernel(const int* __restrict__ src, const int* __restrict__ dst,
                            int* __restrict__ fill_pos, int* __restrict__ esrc) {
    int i = blockIdx.x * 256 + threadIdx.x;
    if (i < N_EDGES) {
        int p = atomicAdd(&fill_pos[dst[i]], 1);
        esrc[p] = src[i];
    }
}

// ---------------- weight split + bf16 shadow of X's SLP input handled in gemm ----
// layout: [0,16384) fcW | [16384,65536) W(3 layers) | [65536,73728) W_last
__global__ void prep_weights(const float* __restrict__ fcW, const float* __restrict__ W,
                             const float* __restrict__ Wl, unsigned short* __restrict__ hi,
                             unsigned short* __restrict__ lo) {
    int i = blockIdx.x * 256 + threadIdx.x;
    float v;
    if (i < 16384) v = fcW[i];
    else if (i < 65536) v = W[i - 16384];
    else if (i < 73728) v = Wl[i - 65536];
    else return;
    unsigned short h = f2bf(v);
    hi[i] = h;
    lo[i] = f2bf(v - bf2f(h));
}

// ---------------- Aggregation: u = (1+eps)*h + mean_{in}(h) ----------------
// One wave per node. Gather payload = bf16 rows (256 B, 1 dword/lane);
// fp32 accumulate; self term read fp32 (sequential, cheap, dominant term).

__global__ void agg_kernel(const float* __restrict__ h, const unsigned short* __restrict__ hbf,
                           const int* __restrict__ row_ptr, const int* __restrict__ esrc,
                           const float* __restrict__ eps, int layer, float* __restrict__ u) {
    int gtid = blockIdx.x * 256 + threadIdx.x;
    int node = gtid >> 6;
    int lane = threadIdx.x & 63;
    if (node >= N_NODES) return;
    node = __builtin_amdgcn_readfirstlane(node);
    int beg = __builtin_amdgcn_readfirstlane(row_ptr[node]);
    int end = __builtin_amdgcn_readfirstlane(row_ptr[node + 1]);

    const unsigned short* hl = hbf + lane * 2;
    float a0x = 0.f, a0y = 0.f, a1x = 0.f, a1y = 0.f;
    float a2x = 0.f, a2y = 0.f, a3x = 0.f, a3y = 0.f;
    int e = beg;
    for (; e + 3 < end; e += 4) {
        int s0 = esrc[e], s1 = esrc[e + 1], s2 = esrc[e + 2], s3 = esrc[e + 3];
        unsigned v0 = *(const unsigned*)(hl + (size_t)s0 * 128);
        unsigned v1 = *(const unsigned*)(hl + (size_t)s1 * 128);
        unsigned v2 = *(const unsigned*)(hl + (size_t)s2 * 128);
        unsigned v3 = *(const unsigned*)(hl + (size_t)s3 * 128);
        a0x += bf2f((unsigned short)v0); a0y += bf2f((unsigned short)(v0 >> 16));
        a1x += bf2f((unsigned short)v1); a1y += bf2f((unsigned short)(v1 >> 16));
        a2x += bf2f((unsigned short)v2); a2y += bf2f((unsigned short)(v2 >> 16));
        a3x += bf2f((unsigned short)v3); a3y += bf2f((unsigned short)(v3 >> 16));
    }
    for (; e < end; e++) {
        int s = esrc[e];
        unsigned v = *(const unsigned*)(hl + (size_t)s * 128);
        a0x += bf2f((unsigned short)v);
        a0y += bf2f((unsigned short)(v >> 16));
    }
    float sx = (a0x + a1x) + (a2x + a3x);
    float sy = (a0y + a1y) + (a2y + a3y);
    int d = end - beg;
    float inv = (d > 0) ? 1.0f / (float)d : 0.0f;
    float ep = 1.0f + eps[layer];
    float2 hv = *(const float2*)(h + (size_t)node * 128 + lane * 2);
    float2 r;
    r.x = ep * hv.x + sx * inv;
    r.y = ep * hv.y + sy * inv;
    *(float2*)(u + (size_t)node * 128 + lane * 2) = r;
}

// ---------------- split-bf16 MFMA GEMM ----------------
// D = Ahi*Whi + Alo*Whi + Ahi*Wlo (missing Alo*Wlo ~ 2^-18 rel).
// Block = 4 waves = 64 rows. Optionally also writes bf16 shadow (next layer's
// gather payload) in the epilogue.

template <int COLS, bool RELU, bool WRITE_BF>
__global__ void __launch_bounds__(256) gemm_mfma(const float* __restrict__ U,
                                                 const unsigned short* __restrict__ Whi,
                                                 const unsigned short* __restrict__ Wlo,
                                                 const float* __restrict__ bias,
                                                 float* __restrict__ out,
                                                 unsigned short* __restrict__ outbf, int nrows) {
    int wave = threadIdx.x >> 6;
    int lane = threadIdx.x & 63;
    int m = lane & 15;
    int quad = lane >> 4;
    int r0 = blockIdx.x * 64 + wave * 16;
    int rowA = r0 + m;
    if (rowA >= nrows) rowA = nrows - 1;  // clamp OOB loads (stores guarded)

    short8 ahi[4], alo[4];
    const float* arow = U + (size_t)rowA * 128 + quad * 8;
#pragma unroll
    for (int kc = 0; kc < 4; kc++) {
        float4 f0 = *(const float4*)(arow + kc * 32);
        float4 f1 = *(const float4*)(arow + kc * 32 + 4);
        float fv[8] = {f0.x, f0.y, f0.z, f0.w, f1.x, f1.y, f1.z, f1.w};
#pragma unroll
        for (int j = 0; j < 8; j++) {
            unsigned short h = f2bf(fv[j]);
            ahi[kc][j] = (short)h;
            alo[kc][j] = (short)f2bf(fv[j] - bf2f(h));
        }
    }

#pragma unroll
    for (int nt = 0; nt < COLS / 16; nt++) {
        int n = nt * 16 + m;
        const unsigned short* bhp = Whi + (size_t)n * 128 + quad * 8;
        const unsigned short* blp = Wlo + (size_t)n * 128 + quad * 8;
        float4v acc = {0.f, 0.f, 0.f, 0.f};
#pragma unroll
        for (int kc = 0; kc < 4; kc++) {
            short8 bh = *(const short8*)(bhp + kc * 32);
            short8 bl = *(const short8*)(blp + kc * 32);
            acc = __builtin_amdgcn_mfma_f32_16x16x32_bf16(ahi[kc], bh, acc, 0, 0, 0);
            acc = __builtin_amdgcn_mfma_f32_16x16x32_bf16(alo[kc], bh, acc, 0, 0, 0);
            acc = __builtin_amdgcn_mfma_f32_16x16x32_bf16(ahi[kc], bl, acc, 0, 0, 0);
        }
        float bv = bias[n];
#pragma unroll
        for (int i = 0; i < 4; i++) {
            int r = r0 + quad * 4 + i;
            if (r < nrows) {
                float v = acc[i] + bv;
                if (RELU) v = fmaxf(v, 0.f);
                out[(size_t)r * COLS + n] = v;
                if (WRITE_BF) outbf[(size_t)r * COLS + n] = f2bf(v);
            }
        }
    }
}

// ---------------- launch ----------------

extern "C" void kernel_launch(void* const* d_in, const int* in_sizes, int n_in,
                              void* d_out, int out_size, void* d_ws, size_t ws_size,
                              hipStream_t stream) {
    const float* X   = (const float*)d_in[0];
    const float* fcW = (const float*)d_in[1];
    const float* fcb = (const float*)d_in[2];
    const float* W   = (const float*)d_in[3];
    const float* b   = (const float*)d_in[4];
    const float* Wl  = (const float*)d_in[5];
    const float* bl  = (const float*)d_in[6];
    const float* eps = (const float*)d_in[7];
    const int* src   = (const int*)d_in[8];
    const int* dst   = (const int*)d_in[9];
    float* out = (float*)d_out;

    // workspace carve (~68 MB)
    float* h = (float*)d_ws;                              // 50000*128 f32
    float* u = h + (size_t)N_NODES * 128;                 // 50000*128 f32
    unsigned short* hbf = (unsigned short*)(u + (size_t)N_NODES * 128);  // 50000*128 bf16
    unsigned short* whi = hbf + (size_t)N_NODES * 128;    // 73728 bf16
    unsigned short* wlo = whi + 73728;                    // 73728 bf16
    int* deg      = (int*)(wlo + 73728);
    int* row_ptr  = deg + N_NODES;                        // N_NODES+1
    int* fill_pos = row_ptr + (N_NODES + 1);
    int* partial  = fill_pos + N_NODES;                   // 256
    int* esrc     = partial + 256;                        // N_EDGES

    const int NB = (N_NODES + 255) / 256;  // 196

    prep_weights<<<(73728 + 255) / 256, 256, 0, stream>>>(fcW, W, Wl, whi, wlo);

    hipMemsetAsync(deg, 0, N_NODES * sizeof(int), stream);
    hist_kernel<<<N_EDGES / 256, 256, 0, stream>>>(dst, deg);
    scan_partial<<<NB, 256, 0, stream>>>(deg, partial);
    scan_offsets<<<1, 256, 0, stream>>>(partial, row_ptr, NB);
    scan_final<<<NB, 256, 0, stream>>>(deg, partial, row_ptr, fill_pos);
    fill_kernel<<<N_EDGES / 256, 256, 0, stream>>>(src, dst, fill_pos, esrc);

    const int gemm_blocks = (N_NODES + 63) / 64;            // 782
    const int agg_blocks = (N_NODES * 64 + 255) / 256;      // 12500

    // input SLP: h = relu(X @ fcW^T + fcb), + bf16 shadow
    gemm_mfma<128, true, true><<<gemm_blocks, 256, 0, stream>>>(X, whi, wlo, fcb, h, hbf,
                                                                N_NODES);

    // 3 hidden GIN layers
    for (int i = 0; i < 3; i++) {
        agg_kernel<<<agg_blocks, 256, 0, stream>>>(h, hbf, row_ptr, esrc, eps, i, u);
        gemm_mfma<128, true, true><<<gemm_blocks, 256, 0, stream>>>(
            u, whi + 16384 + (size_t)i * 16384, wlo + 16384 + (size_t)i * 16384,
            b + (size_t)i * 128, h, hbf, N_NODES);
    }

    // last layer (no relu) -> d_out
    agg_kernel<<<agg_blocks, 256, 0, stream>>>(h, hbf, row_ptr, esrc, eps, 3, u);
    gemm_mfma<64, false, false><<<gemm_blocks, 256, 0, stream>>>(u, whi + 65536, wlo + 65536, bl,
                                                                 out, nullptr, N_NODES);
}

// Round 4
// 452.036 us; speedup vs baseline: 1.8427x; 1.0799x over previous
//
#include <hip/hip_runtime.h>

#define N_NODES 50000
#define N_EDGES 800000
#define GRP 8                       // XCD count; group = blockIdx & 7
#define NPG (N_NODES / GRP)         // 6250 nodes per group
#define EPB 8192                    // edges per stripe-block
#define NSTRIPE ((N_EDGES + EPB - 1) / EPB)  // 98

typedef __attribute__((ext_vector_type(8))) short short8;
typedef __attribute__((ext_vector_type(4))) float float4v;

__device__ inline unsigned short f2bf(float f) {
    unsigned u = __float_as_uint(f);
    unsigned r = u + 0x7fff + ((u >> 16) & 1);
    return (unsigned short)(r >> 16);
}
__device__ inline float bf2f(unsigned short h) {
    return __uint_as_float(((unsigned)h) << 16);
}

// ---------------- scan (3-phase, 196 blocks) ----------------

__global__ void scan_partial(const int* __restrict__ deg, int* __restrict__ partial) {
    __shared__ int sm[256];
    int t = threadIdx.x;
    int i = blockIdx.x * 256 + t;
    sm[t] = (i < N_NODES) ? deg[i] : 0;
    __syncthreads();
    for (int o = 128; o > 0; o >>= 1) {
        if (t < o) sm[t] += sm[t + o];
        __syncthreads();
    }
    if (t == 0) partial[blockIdx.x] = sm[0];
}

__global__ void scan_offsets(int* __restrict__ partial, int* __restrict__ row_ptr, int nparts) {
    __shared__ int sm[256];
    int t = threadIdx.x;
    int v = (t < nparts) ? partial[t] : 0;
    sm[t] = v;
    __syncthreads();
    for (int o = 1; o < 256; o <<= 1) {
        int x = sm[t];
        int a = (t >= o) ? sm[t - o] : 0;
        __syncthreads();
        sm[t] = x + a;
        __syncthreads();
    }
    if (t < nparts) partial[t] = sm[t] - v;  // exclusive
    if (t == nparts - 1) row_ptr[N_NODES] = sm[t];
}

__global__ void scan_final(const int* __restrict__ deg, const int* __restrict__ partial,
                           int* __restrict__ row_ptr, int* __restrict__ fill_pos) {
    __shared__ int sm[256];
    int t = threadIdx.x;
    int i = blockIdx.x * 256 + t;
    int v = (i < N_NODES) ? deg[i] : 0;
    sm[t] = v;
    __syncthreads();
    for (int o = 1; o < 256; o <<= 1) {
        int x = sm[t];
        int a = (t >= o) ? sm[t - o] : 0;
        __syncthreads();
        sm[t] = x + a;
        __syncthreads();
    }
    if (i < N_NODES) {
        int ex = sm[t] - v + partial[blockIdx.x];
        row_ptr[i] = ex;
        fill_pos[i] = ex;
    }
}

// ---------------- fused: XCD-grouped hist (784 blocks) + weight split (288) ----------

__global__ void __launch_bounds__(256) fused_hist_prep(
    const int* __restrict__ dst, int* __restrict__ deg, const float* __restrict__ fcW,
    const float* __restrict__ W, const float* __restrict__ Wl, unsigned short* __restrict__ hi,
    unsigned short* __restrict__ lo) {
    int bx = blockIdx.x;
    if (bx < GRP * NSTRIPE) {
        // grouped histogram: group owns dst range; its atomic lines stay on one XCD
        int g = bx & 7;
        int stripe = bx >> 3;
        int nlo = g * NPG, nhi = nlo + NPG;
        int base = stripe * EPB + threadIdx.x;
#pragma unroll 4
        for (int k = 0; k < EPB / 256; k++) {
            int i = base + k * 256;
            if (i < N_EDGES) {
                int d = dst[i];
                if (d >= nlo && d < nhi) atomicAdd(&deg[d], 1);
            }
        }
    } else {
        // weight split: [0,16384) fcW | [16384,65536) W | [65536,73728) W_last
        int i = (bx - GRP * NSTRIPE) * 256 + threadIdx.x;
        float v;
        if (i < 16384) v = fcW[i];
        else if (i < 65536) v = W[i - 16384];
        else if (i < 73728) v = Wl[i - 65536];
        else return;
        unsigned short h = f2bf(v);
        hi[i] = h;
        lo[i] = f2bf(v - bf2f(h));
    }
}

// ---------------- split-bf16 MFMA GEMM body ----------------
// D = Ahi*Whi + Alo*Whi + Ahi*Wlo (missing Alo*Wlo ~ 2^-18 rel).
// Block = 4 waves = 64 rows. Optionally writes bf16 shadow (next gather payload).

template <int COLS, bool RELU, bool WRITE_BF>
__device__ __forceinline__ void gemm_body(int bx, const float* __restrict__ U,
                                          const unsigned short* __restrict__ Whi,
                                          const unsigned short* __restrict__ Wlo,
                                          const float* __restrict__ bias, float* __restrict__ out,
                                          unsigned short* __restrict__ outbf, int nrows) {
    int wave = threadIdx.x >> 6;
    int lane = threadIdx.x & 63;
    int m = lane & 15;
    int quad = lane >> 4;
    int r0 = bx * 64 + wave * 16;
    int rowA = r0 + m;
    if (rowA >= nrows) rowA = nrows - 1;  // clamp OOB loads (stores guarded)

    short8 ahi[4], alo[4];
    const float* arow = U + (size_t)rowA * 128 + quad * 8;
#pragma unroll
    for (int kc = 0; kc < 4; kc++) {
        float4 f0 = *(const float4*)(arow + kc * 32);
        float4 f1 = *(const float4*)(arow + kc * 32 + 4);
        float fv[8] = {f0.x, f0.y, f0.z, f0.w, f1.x, f1.y, f1.z, f1.w};
#pragma unroll
        for (int j = 0; j < 8; j++) {
            unsigned short h = f2bf(fv[j]);
            ahi[kc][j] = (short)h;
            alo[kc][j] = (short)f2bf(fv[j] - bf2f(h));
        }
    }

#pragma unroll
    for (int nt = 0; nt < COLS / 16; nt++) {
        int n = nt * 16 + m;
        const unsigned short* bhp = Whi + (size_t)n * 128 + quad * 8;
        const unsigned short* blp = Wlo + (size_t)n * 128 + quad * 8;
        float4v acc = {0.f, 0.f, 0.f, 0.f};
#pragma unroll
        for (int kc = 0; kc < 4; kc++) {
            short8 bh = *(const short8*)(bhp + kc * 32);
            short8 bl = *(const short8*)(blp + kc * 32);
            acc = __builtin_amdgcn_mfma_f32_16x16x32_bf16(ahi[kc], bh, acc, 0, 0, 0);
            acc = __builtin_amdgcn_mfma_f32_16x16x32_bf16(alo[kc], bh, acc, 0, 0, 0);
            acc = __builtin_amdgcn_mfma_f32_16x16x32_bf16(ahi[kc], bl, acc, 0, 0, 0);
        }
        float bv = bias[n];
#pragma unroll
        for (int i = 0; i < 4; i++) {
            int r = r0 + quad * 4 + i;
            if (r < nrows) {
                float v = acc[i] + bv;
                if (RELU) v = fmaxf(v, 0.f);
                out[(size_t)r * COLS + n] = v;
                if (WRITE_BF) outbf[(size_t)r * COLS + n] = f2bf(v);
            }
        }
    }
}

template <int COLS, bool RELU, bool WRITE_BF>
__global__ void __launch_bounds__(256) gemm_mfma(const float* __restrict__ U,
                                                 const unsigned short* __restrict__ Whi,
                                                 const unsigned short* __restrict__ Wlo,
                                                 const float* __restrict__ bias,
                                                 float* __restrict__ out,
                                                 unsigned short* __restrict__ outbf, int nrows) {
    gemm_body<COLS, RELU, WRITE_BF>(blockIdx.x, U, Whi, Wlo, bias, out, outbf, nrows);
}

// ---------------- fused: XCD-grouped CSR fill (784 blocks, first) + SLP GEMM (782) ----

__global__ void __launch_bounds__(256) fused_fill_gemm(
    const int* __restrict__ src, const int* __restrict__ dst, int* __restrict__ fill_pos,
    int* __restrict__ esrc, const float* __restrict__ X, const unsigned short* __restrict__ whi,
    const unsigned short* __restrict__ wlo, const float* __restrict__ fcb, float* __restrict__ h,
    unsigned short* __restrict__ hbf) {
    int bx = blockIdx.x;
    if (bx < GRP * NSTRIPE) {
        // grouped fill: group's fill_pos lines + esrc region written by one XCD only
        int g = bx & 7;
        int stripe = bx >> 3;
        int nlo = g * NPG, nhi = nlo + NPG;
        int base = stripe * EPB + threadIdx.x;
#pragma unroll 4
        for (int k = 0; k < EPB / 256; k++) {
            int i = base + k * 256;
            if (i < N_EDGES) {
                int d = dst[i];
                if (d >= nlo && d < nhi) {
                    int p = atomicAdd(&fill_pos[d], 1);
                    esrc[p] = src[i];
                }
            }
        }
    } else {
        gemm_body<128, true, true>(bx - GRP * NSTRIPE, X, whi, wlo, fcb, h, hbf, N_NODES);
    }
}

// ---------------- Aggregation: u = (1+eps)*h + mean_{in}(h) ----------------
// One wave per node; bf16 gather payload (256 B/row), fp32 accumulate + fp32 self term.

__global__ void agg_kernel(const float* __restrict__ h, const unsigned short* __restrict__ hbf,
                           const int* __restrict__ row_ptr, const int* __restrict__ esrc,
                           const float* __restrict__ eps, int layer, float* __restrict__ u) {
    int gtid = blockIdx.x * 256 + threadIdx.x;
    int node = gtid >> 6;
    int lane = threadIdx.x & 63;
    if (node >= N_NODES) return;
    node = __builtin_amdgcn_readfirstlane(node);
    int beg = __builtin_amdgcn_readfirstlane(row_ptr[node]);
    int end = __builtin_amdgcn_readfirstlane(row_ptr[node + 1]);

    const unsigned short* hl = hbf + lane * 2;
    float a0x = 0.f, a0y = 0.f, a1x = 0.f, a1y = 0.f;
    float a2x = 0.f, a2y = 0.f, a3x = 0.f, a3y = 0.f;
    int e = beg;
    for (; e + 3 < end; e += 4) {
        int s0 = esrc[e], s1 = esrc[e + 1], s2 = esrc[e + 2], s3 = esrc[e + 3];
        unsigned v0 = *(const unsigned*)(hl + (size_t)s0 * 128);
        unsigned v1 = *(const unsigned*)(hl + (size_t)s1 * 128);
        unsigned v2 = *(const unsigned*)(hl + (size_t)s2 * 128);
        unsigned v3 = *(const unsigned*)(hl + (size_t)s3 * 128);
        a0x += bf2f((unsigned short)v0); a0y += bf2f((unsigned short)(v0 >> 16));
        a1x += bf2f((unsigned short)v1); a1y += bf2f((unsigned short)(v1 >> 16));
        a2x += bf2f((unsigned short)v2); a2y += bf2f((unsigned short)(v2 >> 16));
        a3x += bf2f((unsigned short)v3); a3y += bf2f((unsigned short)(v3 >> 16));
    }
    for (; e < end; e++) {
        int s = esrc[e];
        unsigned v = *(const unsigned*)(hl + (size_t)s * 128);
        a0x += bf2f((unsigned short)v);
        a0y += bf2f((unsigned short)(v >> 16));
    }
    float sx = (a0x + a1x) + (a2x + a3x);
    float sy = (a0y + a1y) + (a2y + a3y);
    int d = end - beg;
    float inv = (d > 0) ? 1.0f / (float)d : 0.0f;
    float ep = 1.0f + eps[layer];
    float2 hv = *(const float2*)(h + (size_t)node * 128 + lane * 2);
    float2 r;
    r.x = ep * hv.x + sx * inv;
    r.y = ep * hv.y + sy * inv;
    *(float2*)(u + (size_t)node * 128 + lane * 2) = r;
}

// ---------------- launch ----------------

extern "C" void kernel_launch(void* const* d_in, const int* in_sizes, int n_in,
                              void* d_out, int out_size, void* d_ws, size_t ws_size,
                              hipStream_t stream) {
    const float* X   = (const float*)d_in[0];
    const float* fcW = (const float*)d_in[1];
    const float* fcb = (const float*)d_in[2];
    const float* W   = (const float*)d_in[3];
    const float* b   = (const float*)d_in[4];
    const float* Wl  = (const float*)d_in[5];
    const float* bl  = (const float*)d_in[6];
    const float* eps = (const float*)d_in[7];
    const int* src   = (const int*)d_in[8];
    const int* dst   = (const int*)d_in[9];
    float* out = (float*)d_out;

    // workspace carve (~68 MB)
    float* h = (float*)d_ws;                              // 50000*128 f32
    float* u = h + (size_t)N_NODES * 128;                 // 50000*128 f32
    unsigned short* hbf = (unsigned short*)(u + (size_t)N_NODES * 128);  // 50000*128 bf16
    unsigned short* whi = hbf + (size_t)N_NODES * 128;    // 73728 bf16
    unsigned short* wlo = whi + 73728;                    // 73728 bf16
    int* deg      = (int*)(wlo + 73728);
    int* row_ptr  = deg + N_NODES;                        // N_NODES+1
    int* fill_pos = row_ptr + (N_NODES + 1);
    int* partial  = fill_pos + N_NODES;                   // 256
    int* esrc     = partial + 256;                        // N_EDGES

    const int NB = (N_NODES + 255) / 256;        // 196
    const int gemm_blocks = (N_NODES + 63) / 64; // 782
    const int agg_blocks = (N_NODES * 64 + 255) / 256;  // 12500
    const int hist_blocks = GRP * NSTRIPE;       // 784
    const int prep_blocks = (73728 + 255) / 256; // 288

    hipMemsetAsync(deg, 0, N_NODES * sizeof(int), stream);
    fused_hist_prep<<<hist_blocks + prep_blocks, 256, 0, stream>>>(dst, deg, fcW, W, Wl, whi, wlo);
    scan_partial<<<NB, 256, 0, stream>>>(deg, partial);
    scan_offsets<<<1, 256, 0, stream>>>(partial, row_ptr, NB);
    scan_final<<<NB, 256, 0, stream>>>(deg, partial, row_ptr, fill_pos);

    // CSR fill + input SLP (independent; one launch)
    fused_fill_gemm<<<hist_blocks + gemm_blocks, 256, 0, stream>>>(src, dst, fill_pos, esrc, X,
                                                                   whi, wlo, fcb, h, hbf);

    // 3 hidden GIN layers
    for (int i = 0; i < 3; i++) {
        agg_kernel<<<agg_blocks, 256, 0, stream>>>(h, hbf, row_ptr, esrc, eps, i, u);
        gemm_mfma<128, true, true><<<gemm_blocks, 256, 0, stream>>>(
            u, whi + 16384 + (size_t)i * 16384, wlo + 16384 + (size_t)i * 16384,
            b + (size_t)i * 128, h, hbf, N_NODES);
    }

    // last layer (no relu) -> d_out
    agg_kernel<<<agg_blocks, 256, 0, stream>>>(h, hbf, row_ptr, esrc, eps, 3, u);
    gemm_mfma<64, false, false><<<gemm_blocks, 256, 0, stream>>>(u, whi + 65536, wlo + 65536, bl,
                                                                 out, nullptr, N_NODES);
}

// Round 5
// 429.726 us; speedup vs baseline: 1.9384x; 1.0519x over previous
//
#include <hip/hip_runtime.h>

#define N_NODES 50000
#define N_EDGES 800000
#define NBUCK 196                   // buckets of 256 nodes: bucket = dst >> 8
#define EPB 8192                    // edges per stripe-block in pass A
#define NSTRIPE ((N_EDGES + EPB - 1) / EPB)  // 98

typedef __attribute__((ext_vector_type(8))) short short8;
typedef __attribute__((ext_vector_type(4))) float float4v;

__device__ inline unsigned short f2bf(float f) {
    unsigned u = __float_as_uint(f);
    unsigned r = u + 0x7fff + ((u >> 16) & 1);
    return (unsigned short)(r >> 16);
}
__device__ inline float bf2f(unsigned short h) {
    return __uint_as_float(((unsigned)h) << 16);
}

// ---------------- fused: bucket histogram (98 blocks) + weight split (288) ----------

__global__ void __launch_bounds__(256) fused_hist_prep(
    const int* __restrict__ dst, int* __restrict__ bcnt, const float* __restrict__ fcW,
    const float* __restrict__ W, const float* __restrict__ Wl, unsigned short* __restrict__ hi,
    unsigned short* __restrict__ lo) {
    int bx = blockIdx.x;
    if (bx < NSTRIPE) {
        __shared__ int lhist[256];
        int t = threadIdx.x;
        lhist[t] = 0;
        __syncthreads();
        int base = bx * EPB + t;
#pragma unroll 4
        for (int k = 0; k < EPB / 256; k++) {
            int i = base + k * 256;
            if (i < N_EDGES) atomicAdd(&lhist[((unsigned)dst[i]) >> 8], 1);
        }
        __syncthreads();
        if (t < NBUCK) atomicAdd(&bcnt[t], lhist[t]);
    } else {
        // weight split: [0,16384) fcW | [16384,65536) W | [65536,73728) W_last
        int i = (bx - NSTRIPE) * 256 + threadIdx.x;
        float v;
        if (i < 16384) v = fcW[i];
        else if (i < 65536) v = W[i - 16384];
        else if (i < 73728) v = Wl[i - 65536];
        else return;
        unsigned short h = f2bf(v);
        hi[i] = h;
        lo[i] = f2bf(v - bf2f(h));
    }
}

// ---------------- bucket offsets (1 block) ----------------

__global__ void bucket_scan(const int* __restrict__ bcnt, int* __restrict__ boff,
                            int* __restrict__ cursor, int* __restrict__ row_ptr) {
    __shared__ int sm[256];
    int t = threadIdx.x;
    int v = (t < NBUCK) ? bcnt[t] : 0;
    sm[t] = v;
    __syncthreads();
    for (int o = 1; o < 256; o <<= 1) {
        int x = sm[t];
        int a = (t >= o) ? sm[t - o] : 0;
        __syncthreads();
        sm[t] = x + a;
        __syncthreads();
    }
    if (t < NBUCK) {
        boff[t] = sm[t] - v;
        cursor[t] = sm[t] - v;
    }
    if (t == NBUCK - 1) {
        boff[NBUCK] = sm[t];
        row_ptr[N_NODES] = sm[t];
    }
}

// ---------------- split-bf16 MFMA GEMM body ----------------
// D = Ahi*Whi + Alo*Whi + Ahi*Wlo (missing Alo*Wlo ~ 2^-18 rel).
// Block = 4 waves = 64 rows. Optionally writes bf16 shadow (next gather payload).

template <int COLS, bool RELU, bool WRITE_BF>
__device__ __forceinline__ void gemm_body(int bx, const float* __restrict__ U,
                                          const unsigned short* __restrict__ Whi,
                                          const unsigned short* __restrict__ Wlo,
                                          const float* __restrict__ bias, float* __restrict__ out,
                                          unsigned short* __restrict__ outbf, int nrows) {
    int wave = threadIdx.x >> 6;
    int lane = threadIdx.x & 63;
    int m = lane & 15;
    int quad = lane >> 4;
    int r0 = bx * 64 + wave * 16;
    int rowA = r0 + m;
    if (rowA >= nrows) rowA = nrows - 1;  // clamp OOB loads (stores guarded)

    short8 ahi[4], alo[4];
    const float* arow = U + (size_t)rowA * 128 + quad * 8;
#pragma unroll
    for (int kc = 0; kc < 4; kc++) {
        float4 f0 = *(const float4*)(arow + kc * 32);
        float4 f1 = *(const float4*)(arow + kc * 32 + 4);
        float fv[8] = {f0.x, f0.y, f0.z, f0.w, f1.x, f1.y, f1.z, f1.w};
#pragma unroll
        for (int j = 0; j < 8; j++) {
            unsigned short h = f2bf(fv[j]);
            ahi[kc][j] = (short)h;
            alo[kc][j] = (short)f2bf(fv[j] - bf2f(h));
        }
    }

#pragma unroll
    for (int nt = 0; nt < COLS / 16; nt++) {
        int n = nt * 16 + m;
        const unsigned short* bhp = Whi + (size_t)n * 128 + quad * 8;
        const unsigned short* blp = Wlo + (size_t)n * 128 + quad * 8;
        float4v acc = {0.f, 0.f, 0.f, 0.f};
#pragma unroll
        for (int kc = 0; kc < 4; kc++) {
            short8 bh = *(const short8*)(bhp + kc * 32);
            short8 bl = *(const short8*)(blp + kc * 32);
            acc = __builtin_amdgcn_mfma_f32_16x16x32_bf16(ahi[kc], bh, acc, 0, 0, 0);
            acc = __builtin_amdgcn_mfma_f32_16x16x32_bf16(alo[kc], bh, acc, 0, 0, 0);
            acc = __builtin_amdgcn_mfma_f32_16x16x32_bf16(ahi[kc], bl, acc, 0, 0, 0);
        }
        float bv = bias[n];
#pragma unroll
        for (int i = 0; i < 4; i++) {
            int r = r0 + quad * 4 + i;
            if (r < nrows) {
                float v = acc[i] + bv;
                if (RELU) v = fmaxf(v, 0.f);
                out[(size_t)r * COLS + n] = v;
                if (WRITE_BF) outbf[(size_t)r * COLS + n] = f2bf(v);
            }
        }
    }
}

template <int COLS, bool RELU, bool WRITE_BF>
__global__ void __launch_bounds__(256) gemm_mfma(const float* __restrict__ U,
                                                 const unsigned short* __restrict__ Whi,
                                                 const unsigned short* __restrict__ Wlo,
                                                 const float* __restrict__ bias,
                                                 float* __restrict__ out,
                                                 unsigned short* __restrict__ outbf, int nrows) {
    gemm_body<COLS, RELU, WRITE_BF>(blockIdx.x, U, Whi, Wlo, bias, out, outbf, nrows);
}

// ---------------- fused: pass A binning (98 blocks) + SLP GEMM (782) ----------
// Pass A: LDS-count stripe's edges per bucket, reserve dense runs via one global
// atomic per bucket, then write packed (localdst<<16 | src) to reserved slots.
// Stores are sequential runs -> full-line writes, no amplification.

__global__ void __launch_bounds__(256) fused_binA_gemm(
    const int* __restrict__ src, const int* __restrict__ dst, int* __restrict__ cursor,
    int* __restrict__ packed, const float* __restrict__ X, const unsigned short* __restrict__ whi,
    const unsigned short* __restrict__ wlo, const float* __restrict__ fcb, float* __restrict__ h,
    unsigned short* __restrict__ hbf) {
    int bx = blockIdx.x;
    if (bx < NSTRIPE) {
        __shared__ int lcount[256];
        __shared__ int lbase[256];
        int t = threadIdx.x;
        lcount[t] = 0;
        __syncthreads();
        int base = bx * EPB + t;
#pragma unroll 4
        for (int k = 0; k < EPB / 256; k++) {
            int i = base + k * 256;
            if (i < N_EDGES) atomicAdd(&lcount[((unsigned)dst[i]) >> 8], 1);
        }
        __syncthreads();
        if (t < NBUCK) {
            lbase[t] = atomicAdd(&cursor[t], lcount[t]);
            lcount[t] = 0;
        }
        __syncthreads();
#pragma unroll 4
        for (int k = 0; k < EPB / 256; k++) {
            int i = base + k * 256;
            if (i < N_EDGES) {
                int d = dst[i];
                int wb = ((unsigned)d) >> 8;
                int p = lbase[wb] + atomicAdd(&lcount[wb], 1);
                packed[p] = ((d & 255) << 16) | src[i];
            }
        }
    } else {
        gemm_body<128, true, true>(bx - NSTRIPE, X, whi, wlo, fcb, h, hbf, N_NODES);
    }
}

// ---------------- pass B: per-bucket counting sort -> row_ptr + esrc ----------
// One block per bucket. All scatter confined to the bucket's ~16 KB region.

__global__ void __launch_bounds__(256) binB_kernel(const int* __restrict__ packed,
                                                   const int* __restrict__ boff,
                                                   int* __restrict__ row_ptr,
                                                   int* __restrict__ esrc) {
    __shared__ int sm[256];
    __shared__ int curs[256];
    int b = blockIdx.x;
    int t = threadIdx.x;
    int e0 = boff[b], e1 = boff[b + 1];
    curs[t] = 0;  // use as histogram first
    __syncthreads();
    for (int i = e0 + t; i < e1; i += 256) atomicAdd(&curs[((unsigned)packed[i]) >> 16], 1);
    __syncthreads();
    int v = curs[t];
    sm[t] = v;
    __syncthreads();
    for (int o = 1; o < 256; o <<= 1) {
        int x = sm[t];
        int a = (t >= o) ? sm[t - o] : 0;
        __syncthreads();
        sm[t] = x + a;
        __syncthreads();
    }
    int excl = sm[t] - v;
    curs[t] = excl;
    int node = b * 256 + t;
    if (node < N_NODES) row_ptr[node] = e0 + excl;
    __syncthreads();
    for (int i = e0 + t; i < e1; i += 256) {
        unsigned w = (unsigned)packed[i];
        int p = atomicAdd(&curs[w >> 16], 1);
        esrc[e0 + p] = (int)(w & 0xFFFFu);
    }
}

// ---------------- Aggregation: u = (1+eps)*h + mean_{in}(h) ----------------
// One wave per node; bf16 gather payload (256 B/row), fp32 accumulate + fp32 self term.

__global__ void agg_kernel(const float* __restrict__ h, const unsigned short* __restrict__ hbf,
                           const int* __restrict__ row_ptr, const int* __restrict__ esrc,
                           const float* __restrict__ eps, int layer, float* __restrict__ u) {
    int gtid = blockIdx.x * 256 + threadIdx.x;
    int node = gtid >> 6;
    int lane = threadIdx.x & 63;
    if (node >= N_NODES) return;
    node = __builtin_amdgcn_readfirstlane(node);
    int beg = __builtin_amdgcn_readfirstlane(row_ptr[node]);
    int end = __builtin_amdgcn_readfirstlane(row_ptr[node + 1]);

    const unsigned short* hl = hbf + lane * 2;
    float a0x = 0.f, a0y = 0.f, a1x = 0.f, a1y = 0.f;
    float a2x = 0.f, a2y = 0.f, a3x = 0.f, a3y = 0.f;
    int e = beg;
    for (; e + 3 < end; e += 4) {
        int s0 = esrc[e], s1 = esrc[e + 1], s2 = esrc[e + 2], s3 = esrc[e + 3];
        unsigned v0 = *(const unsigned*)(hl + (size_t)s0 * 128);
        unsigned v1 = *(const unsigned*)(hl + (size_t)s1 * 128);
        unsigned v2 = *(const unsigned*)(hl + (size_t)s2 * 128);
        unsigned v3 = *(const unsigned*)(hl + (size_t)s3 * 128);
        a0x += bf2f((unsigned short)v0); a0y += bf2f((unsigned short)(v0 >> 16));
        a1x += bf2f((unsigned short)v1); a1y += bf2f((unsigned short)(v1 >> 16));
        a2x += bf2f((unsigned short)v2); a2y += bf2f((unsigned short)(v2 >> 16));
        a3x += bf2f((unsigned short)v3); a3y += bf2f((unsigned short)(v3 >> 16));
    }
    for (; e < end; e++) {
        int s = esrc[e];
        unsigned v = *(const unsigned*)(hl + (size_t)s * 128);
        a0x += bf2f((unsigned short)v);
        a0y += bf2f((unsigned short)(v >> 16));
    }
    float sx = (a0x + a1x) + (a2x + a3x);
    float sy = (a0y + a1y) + (a2y + a3y);
    int d = end - beg;
    float inv = (d > 0) ? 1.0f / (float)d : 0.0f;
    float ep = 1.0f + eps[layer];
    float2 hv = *(const float2*)(h + (size_t)node * 128 + lane * 2);
    float2 r;
    r.x = ep * hv.x + sx * inv;
    r.y = ep * hv.y + sy * inv;
    *(float2*)(u + (size_t)node * 128 + lane * 2) = r;
}

// ---------------- launch ----------------

extern "C" void kernel_launch(void* const* d_in, const int* in_sizes, int n_in,
                              void* d_out, int out_size, void* d_ws, size_t ws_size,
                              hipStream_t stream) {
    const float* X   = (const float*)d_in[0];
    const float* fcW = (const float*)d_in[1];
    const float* fcb = (const float*)d_in[2];
    const float* W   = (const float*)d_in[3];
    const float* b   = (const float*)d_in[4];
    const float* Wl  = (const float*)d_in[5];
    const float* bl  = (const float*)d_in[6];
    const float* eps = (const float*)d_in[7];
    const int* src   = (const int*)d_in[8];
    const int* dst   = (const int*)d_in[9];
    float* out = (float*)d_out;

    // workspace carve (~71 MB)
    float* h = (float*)d_ws;                              // 50000*128 f32
    float* u = h + (size_t)N_NODES * 128;                 // 50000*128 f32
    unsigned short* hbf = (unsigned short*)(u + (size_t)N_NODES * 128);  // 50000*128 bf16
    unsigned short* whi = hbf + (size_t)N_NODES * 128;    // 73728 bf16
    unsigned short* wlo = whi + 73728;                    // 73728 bf16
    int* bcnt    = (int*)(wlo + 73728);                   // NBUCK
    int* boff    = bcnt + NBUCK;                          // NBUCK+1
    int* cursor  = boff + NBUCK + 1;                      // NBUCK
    int* row_ptr = cursor + NBUCK;                        // N_NODES+1
    int* packed  = row_ptr + N_NODES + 1;                 // N_EDGES
    int* esrc    = packed + N_EDGES;                      // N_EDGES

    const int gemm_blocks = (N_NODES + 63) / 64;        // 782
    const int agg_blocks = (N_NODES * 64 + 255) / 256;  // 12500
    const int prep_blocks = (73728 + 255) / 256;        // 288

    hipMemsetAsync(bcnt, 0, NBUCK * sizeof(int), stream);
    fused_hist_prep<<<NSTRIPE + prep_blocks, 256, 0, stream>>>(dst, bcnt, fcW, W, Wl, whi, wlo);
    bucket_scan<<<1, 256, 0, stream>>>(bcnt, boff, cursor, row_ptr);
    fused_binA_gemm<<<NSTRIPE + gemm_blocks, 256, 0, stream>>>(src, dst, cursor, packed, X, whi,
                                                               wlo, fcb, h, hbf);
    binB_kernel<<<NBUCK, 256, 0, stream>>>(packed, boff, row_ptr, esrc);

    // 3 hidden GIN layers
    for (int i = 0; i < 3; i++) {
        agg_kernel<<<agg_blocks, 256, 0, stream>>>(h, hbf, row_ptr, esrc, eps, i, u);
        gemm_mfma<128, true, true><<<gemm_blocks, 256, 0, stream>>>(
            u, whi + 16384 + (size_t)i * 16384, wlo + 16384 + (size_t)i * 16384,
            b + (size_t)i * 128, h, hbf, N_NODES);
    }

    // last layer (no relu) -> d_out
    agg_kernel<<<agg_blocks, 256, 0, stream>>>(h, hbf, row_ptr, esrc, eps, 3, u);
    gemm_mfma<64, false, false><<<gemm_blocks, 256, 0, stream>>>(u, whi + 65536, wlo + 65536, bl,
                                                                 out, nullptr, N_NODES);
}